// Round 1
// baseline (725.573 us; speedup 1.0000x reference)
//
#include <hip/hip_runtime.h>

// Fused AttentionAggregator: B=4096, N=64, F=128, H=8, D=64, HD=512.
// out[b,n,c] = relu(lin[b,n,c] * softmax_n(leakyrelu(att))[b, c/64, n])
// lin = x @ W_lin via fp16 MFMA (operand-swapped: A=W cols, B=x rows).
// lin stays register-resident: att partials computed by feeding the phase-B
// accumulator (C-layout) directly as the B-operand of mfma_f32_16x16x16_f16.
//
// This version: PERSISTENT blocks (grid 1024, NBATCH=4 batches each) with
// T14 async-STAGE split: next batch's x is issued as 4x16B nt loads right
// after the GEMM (phase D region) and committed to xs (cvt + ds_write) only
// after the reduction barrier -- HBM latency hides under D/reduce/softmax.
// attbuf no longer aliases xs, dropping the post-GEMM barrier: 3 barriers/iter.
// LDS 56.6 KB; still 2 blocks/CU (VGPR-capped by the 64-reg accumulator).

typedef _Float16 half8  __attribute__((ext_vector_type(8)));
typedef _Float16 half4v __attribute__((ext_vector_type(4)));
typedef float    f32x4  __attribute__((ext_vector_type(4)));

static constexpr int NSEQ   = 64;
static constexpr int FIN    = 128;
static constexpr int HDIM   = 512;   // H*D
static constexpr int NHEAD  = 8;
static constexpr int XS_LD  = 136;   // halves; 272 B/row, b128-aligned, even bank spread
static constexpr int NBATCH = 4;     // batches per persistent block

// smem map (byte offsets):
//   [0, 17408)        xs: x[b] fp16 [64][136]          (read in phase B; rewritten
//                                                       for b+1 after barrier 2)
//   [17408, 52224)    R: attbuf [w][n][j] f32 8x64x16 (first 32768 B, phase D ->
//                        reduction) / ftile per-wave [16][68] f32 x 8 (phase F,
//                        wave-private slices, dead attbuf)
//   [52224, 56576)    att_s: [n][j] f32 64x17          (reduction -> E)
static constexpr int R_OFF      = 17408;
static constexpr int ATT_OFF    = 52224;
static constexpr int SMEM_BYTES = 56576;

// Prep: W_lin (fp32 [128][512]) -> W_linT fp16 [512][128] (k-contiguous);
//       W_att (fp32 [1024][8])  -> waA fp16 [8192]: A-fragment-ordered Wa_cat.
__global__ __launch_bounds__(256) void prep_kernel(const float* __restrict__ wlin,
                                                   const float* __restrict__ watt,
                                                   _Float16* __restrict__ wlinT,
                                                   _Float16* __restrict__ waA)
{
    int t = blockIdx.x * 256 + threadIdx.x;
    if (t < HDIM * FIN) {
        int c = t >> 7;
        int k = t & 127;
        wlinT[t] = (_Float16)wlin[k * HDIM + c];
    }
    if (t < 16 * HDIM) {                 // 8192 waA halves
        int i     = t & 3;
        int lane  = (t >> 2) & 63;
        int slice = t >> 8;              // w*4 + mt, 0..31
        int c = (slice >> 2) * 64 + (slice & 3) * 16 + (lane >> 4) * 4 + i;
        int j = lane & 15;
        float v = (j < NHEAD) ? watt[(HDIM + c) * NHEAD + j]
                              : watt[c * NHEAD + (j - NHEAD)];
        waA[t] = (_Float16)v;
    }
}

__global__ __launch_bounds__(512, 4) void fused_kernel(const float* __restrict__ x,
                                                       const _Float16* __restrict__ wlinT,
                                                       const _Float16* __restrict__ waA,
                                                       const int* __restrict__ mask,
                                                       float* __restrict__ out)
{
    __shared__ char smem[SMEM_BYTES] __attribute__((aligned(16)));
    _Float16* xs     = (_Float16*)smem;
    float*    attbuf = (float*)(smem + R_OFF);
    float*    att_s  = (float*)(smem + ATT_OFF);

    const int t    = threadIdx.x;
    const int lane = t & 63;
    const int w    = t >> 6;       // wave 0..7 == head
    const int l15  = lane & 15;
    const int quad = lane >> 4;    // 0..3

    const int b0 = blockIdx.x * NBATCH;

    // ---- Prologue: stage x[b0] (fp32 64x128) -> xs fp16 [64][136] ----
    {
        const f32x4* xb = (const f32x4*)(x + (size_t)b0 * (NSEQ * FIN));
        #pragma unroll
        for (int j = 0; j < 4; ++j) {
            int i = j * 512 + t;                   // float4 index, 2048 total
            f32x4 v = __builtin_nontemporal_load(&xb[i]);
            int n = i >> 5;
            int k = (i & 31) << 2;
            half4v hv;
            hv[0] = (_Float16)v[0]; hv[1] = (_Float16)v[1];
            hv[2] = (_Float16)v[2]; hv[3] = (_Float16)v[3];
            *(half4v*)(xs + n * XS_LD + k) = hv;
        }
    }
    int mv = mask[b0 * NSEQ + lane];               // current batch's mask bit
    __syncthreads();

    #pragma unroll 1
    for (int it = 0; it < NBATCH; ++it) {
        const int b    = b0 + it;
        const bool more = (it + 1 < NBATCH);

        // ---- Phase B: lin^T GEMM. A = W_linT cols (m), B = x rows (n).
        //      acc[mt][nt] reg i: lin[n = nt*16+l15][c = 64w + mt*16 + quad*4 + i]
        f32x4 acc[4][4];
        #pragma unroll
        for (int mt = 0; mt < 4; ++mt)
            #pragma unroll
            for (int nt = 0; nt < 4; ++nt)
                acc[mt][nt] = (f32x4){0.f, 0.f, 0.f, 0.f};

        const int colbase = w * 64;
        #pragma unroll
        for (int ks = 0; ks < 4; ++ks) {
            const int k0 = ks * 32 + quad * 8;
            half8 a[4];
            #pragma unroll
            for (int mt = 0; mt < 4; ++mt)
                a[mt] = *(const half8*)(wlinT + (colbase + mt * 16 + l15) * FIN + k0);
            #pragma unroll
            for (int nt = 0; nt < 4; ++nt) {
                half8 bfr = *(const half8*)(xs + (nt * 16 + l15) * XS_LD + k0);
                #pragma unroll
                for (int mt = 0; mt < 4; ++mt)
                    acc[mt][nt] = __builtin_amdgcn_mfma_f32_16x16x32_f16(a[mt], bfr, acc[mt][nt], 0, 0, 0);
            }
        }

        // ---- Async-STAGE issue: next batch's x -> registers (nt loads).
        //      First use (cvt+ds_write) is two barriers later: latency hidden
        //      under phase D + reduction + softmax.
        f32x4 stg[4];
        int mv_next = 0;
        if (more) {
            const f32x4* xbn = (const f32x4*)(x + (size_t)(b + 1) * (NSEQ * FIN));
            #pragma unroll
            for (int j = 0; j < 4; ++j)
                stg[j] = __builtin_nontemporal_load(&xbn[j * 512 + t]);
            mv_next = mask[(b + 1) * NSEQ + lane];
        }

        // ---- Phase D: att partials T[j][n] = sum_c Wa_cat[c][j] * lin[n][c]
        //      over this wave's 64 cols, via 16x16x16 MFMA with B = cvt_f16(acc).
        {
            f32x4 T[4];
            #pragma unroll
            for (int nt = 0; nt < 4; ++nt) T[nt] = (f32x4){0.f, 0.f, 0.f, 0.f};
            #pragma unroll
            for (int mt = 0; mt < 4; ++mt) {
                half4v aF = *(const half4v*)(waA + ((w * 4 + mt) * 64 + lane) * 4);
                #pragma unroll
                for (int nt = 0; nt < 4; ++nt) {
                    half4v bF;
                    #pragma unroll
                    for (int i = 0; i < 4; ++i) bF[i] = (_Float16)acc[mt][nt][i];
                    T[nt] = __builtin_amdgcn_mfma_f32_16x16x16f16(aF, bF, T[nt], 0, 0, 0);
                }
            }
            // T[nt] C-layout: row j = quad*4+reg, col n = nt*16+l15 -> attbuf[w][n][j]
            #pragma unroll
            for (int nt = 0; nt < 4; ++nt)
                *(f32x4*)(attbuf + (w * 64 + nt * 16 + l15) * 16 + quad * 4) = T[nt];
        }
        __syncthreads();   // (1) attbuf complete

        // ---- Reduction: att[n][j] = sum_w attbuf[w][n][j] -> att_s [n][17] ----
        {
            int n  = t >> 3;          // 0..63
            int j0 = (t & 7) * 2;     // 0,2,..,14
            float s0 = 0.f, s1 = 0.f;
            #pragma unroll
            for (int ww = 0; ww < 8; ++ww) {
                const float* p = attbuf + (ww * 64 + n) * 16 + j0;
                s0 += p[0]; s1 += p[1];
            }
            att_s[n * 17 + j0]     = s0;
            att_s[n * 17 + j0 + 1] = s1;
        }
        __syncthreads();   // (2) att_s complete; attbuf dead; xs dead (safe to rewrite)

        // ---- Phase E: leakyrelu + mask + softmax over n; wave w -> head w; lane = n ----
        float aw_reg;
        {
            const float pen = (mv == 0) ? -1e9f : 0.0f;
            float a = att_s[lane * 17 + w] + att_s[8 + w];   // lin term + src term (n=0 row)
            a = (a >= 0.0f) ? a : 0.2f * a;                  // leakyrelu BEFORE mask
            a += pen;
            float mx = a;
            #pragma unroll
            for (int off = 32; off > 0; off >>= 1)
                mx = fmaxf(mx, __shfl_xor(mx, off, 64));
            float e = __expf(a - mx);
            float s = e;
            #pragma unroll
            for (int off = 32; off > 0; off >>= 1)
                s += __shfl_xor(s, off, 64);
            aw_reg = e / s;                                  // aw[w][lane]
        }

        // ---- Async-STAGE commit: cvt staged regs -> xs for batch b+1.
        //      (after barrier 2: phase B of this iter long done; next read of xs
        //      is next iter's phase B, after barrier 3.)
        if (more) {
            #pragma unroll
            for (int j = 0; j < 4; ++j) {
                int i = j * 512 + t;
                int n = i >> 5;
                int k = (i & 31) << 2;
                half4v hv;
                hv[0] = (_Float16)stg[j][0]; hv[1] = (_Float16)stg[j][1];
                hv[2] = (_Float16)stg[j][2]; hv[3] = (_Float16)stg[j][3];
                *(half4v*)(xs + n * XS_LD + k) = hv;
            }
        }

        // ---- Phase F: out = relu(lin * aw) from registers, LDS-tile transpose
        //      for coalesced 256 B row segments. ftile aliases dead attbuf;
        //      wave-private slice, no barrier needed.
        {
            float* ft = (float*)(smem + R_OFF) + w * (16 * 68);   // private 4352 B tile
            float* outb = out + (size_t)b * (NSEQ * HDIM);
            #pragma unroll
            for (int nt = 0; nt < 4; ++nt) {
                float awv = __shfl(aw_reg, nt * 16 + l15, 64);    // aw[w][n], n = nt*16+l15
                #pragma unroll
                for (int mt = 0; mt < 4; ++mt) {
                    f32x4 o;
                    #pragma unroll
                    for (int i = 0; i < 4; ++i)
                        o[i] = fmaxf(acc[mt][nt][i] * awv, 0.0f);
                    *(f32x4*)(ft + l15 * 68 + mt * 16 + quad * 4) = o;   // [n_local][c_local]
                }
                #pragma unroll
                for (int s = 0; s < 4; ++s) {
                    int r = s * 4 + quad;                    // n_local
                    f32x4 v = *(const f32x4*)(ft + r * 68 + l15 * 4);
                    int n = nt * 16 + r;
                    __builtin_nontemporal_store(v, (f32x4*)(outb + n * HDIM + w * 64 + l15 * 4));
                }
            }
        }

        mv = mv_next;
        __syncthreads();   // (3) xs[b+1] ready; ftile reads done before next phase D
    }
}

extern "C" void kernel_launch(void* const* d_in, const int* in_sizes, int n_in,
                              void* d_out, int out_size, void* d_ws, size_t ws_size,
                              hipStream_t stream)
{
    const float* x    = (const float*)d_in[0];
    const float* wlin = (const float*)d_in[1];
    const float* watt = (const float*)d_in[2];
    const int*   mask = (const int*)d_in[3];
    float* out = (float*)d_out;

    _Float16* wlinT = (_Float16*)d_ws;             // 65536 halves = 128 KiB
    _Float16* waA   = wlinT + HDIM * FIN;          // 8192 halves = 16 KiB

    const int B = in_sizes[0] / (NSEQ * FIN);      // 4096

    prep_kernel<<<256, 256, 0, stream>>>(wlin, watt, wlinT, waA);
    fused_kernel<<<B / NBATCH, 512, 0, stream>>>(x, wlinT, waA, mask, out);
}